// Round 1
// baseline (2032.866 us; speedup 1.0000x reference)
//
#include <hip/hip_runtime.h>

#define NN 65536
#define EE 1048576
#define TN 32   // nodes per block in fused kernel

// ---------------- style constants (tiny, one block) ----------------
// consts layout (floats):
//   0: g_n0[128]   128: b_n0[128]
// 256: g_f0[128]   384: b_f0[128]
// 512: g_f1[64]    576: b_f1[64]
// 640: eb_n0[128]  768: eb_f0[128]  896: eb_f1[64]
__global__ void style_consts_k(const float* __restrict__ w,
    const float* __restrict__ n0_aW, const float* __restrict__ n0_ab,
    const float* __restrict__ f0_aW, const float* __restrict__ f0_ab,
    const float* __restrict__ f1_aW, const float* __restrict__ f1_ab,
    const float* __restrict__ n0_b, const float* __restrict__ n0_noise, const float* __restrict__ n0_ns,
    const float* __restrict__ f0_b, const float* __restrict__ f0_noise, const float* __restrict__ f0_ns,
    const float* __restrict__ f1_b, const float* __restrict__ f1_noise, const float* __restrict__ f1_ns,
    float* __restrict__ consts)
{
    int t = threadIdx.x;
    for (int j = t; j < 640; j += 256) {
        const float* aW; const float* ab; int row; int off;
        if (j < 256)      { aW = n0_aW; ab = n0_ab; row = j;       off = 0;   }
        else if (j < 512) { aW = f0_aW; ab = f0_ab; row = j - 256; off = 256; }
        else              { aW = f1_aW; ab = f1_ab; row = j - 512; off = 512; }
        float s = 0.f;
        for (int k = 0; k < 128; k++) s += w[k] * aW[row * 128 + k];
        consts[off + row] = s + ab[row];
    }
    if (t < 128) consts[640 + t] = n0_b[t] + n0_noise[t] * n0_ns[0];
    if (t < 128) consts[768 + t] = f0_b[t] + f0_noise[t] * f0_ns[0];
    if (t < 64)  consts[896 + t] = f1_b[t] + f1_noise[t] * f1_ns[0];
}

// ---------------- agg init: agg[i][c] = ba[c] ----------------
__global__ void init_agg_k(float4* __restrict__ agg4, const float4* __restrict__ ba4)
{
    int i = blockIdx.x * 256 + threadIdx.x;   // NN*32 float4s
    agg4[i] = ba4[i & 31];
}

// ---------------- scatter: agg[dst] += Wa[src] ----------------
__global__ void scatter_k(const int* __restrict__ ei, const float4* __restrict__ Wa4,
                          float* __restrict__ agg)
{
    int tt = blockIdx.x * 256 + threadIdx.x;  // EE*32 threads
    int e = tt >> 5, q = tt & 31;
    int src = ei[e];
    int dst = ei[EE + e];
    float4 v = Wa4[(size_t)src * 32 + q];
    float* a = agg + (size_t)dst * 128 + q * 4;
    atomicAdd(a + 0, v.x);
    atomicAdd(a + 1, v.y);
    atomicAdd(a + 2, v.z);
    atomicAdd(a + 3, v.w);
}

// ---------------- fused per-node pipeline ----------------
// 512 threads: c = t>>2 (0..127 output channel), ks = t&3 (k-slice).
// Thread's k-slice = float4 chunks {4*j + ks}. LDS h reads are 4-address
// broadcasts (conflict-free); weight slices live in registers across nodes.
__global__ __launch_bounds__(512) void fused_k(
    const float* __restrict__ x, const float* __restrict__ agg,
    const float* __restrict__ c1W, const float* __restrict__ c1b,
    const float* __restrict__ n0W,
    const float* __restrict__ c2W, const float* __restrict__ c2b,
    const float* __restrict__ f0W, const float* __restrict__ f1W,
    const float* __restrict__ consts, float* __restrict__ out)
{
    __shared__ float bufA[TN * 128];
    __shared__ float bufB[TN * 128];
    __shared__ float bufX[TN * 64];

    const int t = threadIdx.x;
    const int nbase = blockIdx.x * TN;
    const int c = t >> 2, ks = t & 3;
    const int wv = t >> 6, lane = t & 63;

    // stage agg rows and x rows into LDS (coalesced float4)
    {
        const float4* agg4 = (const float4*)agg + (size_t)nbase * 32;
        float4* bA4 = (float4*)bufA;
        for (int i = t; i < TN * 32; i += 512) bA4[i] = agg4[i];
        const float4* xx4 = (const float4*)x + (size_t)nbase * 16;
        float4* bX4 = (float4*)bufX;
        for (int i = t; i < TN * 16; i += 512) bX4[i] = xx4[i];
    }
    __syncthreads();

    // ---- phase 1: bufB = bufA + cat1(bufA) + c1b ----
    {
        float4 Wr[8];
        const float4* W4 = (const float4*)c1W + c * 32;
        #pragma unroll
        for (int j = 0; j < 8; j++) Wr[j] = W4[j * 4 + ks];
        const float bias = c1b[c];
        for (int n = 0; n < TN; n++) {
            const float4* h4 = (const float4*)(bufA + n * 128);
            float y = 0.f;
            #pragma unroll
            for (int j = 0; j < 8; j++) {
                float4 h = h4[j * 4 + ks];
                y += Wr[j].x * h.x + Wr[j].y * h.y + Wr[j].z * h.z + Wr[j].w * h.w;
            }
            y += __shfl_xor(y, 1); y += __shfl_xor(y, 2);
            if (ks == 0) bufB[n * 128 + c] = bufA[n * 128 + c] + y + bias;
        }
    }
    __syncthreads();

    // ---- phase 2: bufA = node0(bufX) + eb_n0 ----
    {
        float4 Wr[4];
        const float4* W4 = (const float4*)n0W + c * 16;
        #pragma unroll
        for (int j = 0; j < 4; j++) Wr[j] = W4[j * 4 + ks];
        const float bias = consts[640 + c];
        for (int n = 0; n < TN; n++) {
            const float4* h4 = (const float4*)(bufX + n * 64);
            float y = 0.f;
            #pragma unroll
            for (int j = 0; j < 4; j++) {
                float4 h = h4[j * 4 + ks];
                y += Wr[j].x * h.x + Wr[j].y * h.y + Wr[j].z * h.z + Wr[j].w * h.w;
            }
            y += __shfl_xor(y, 1); y += __shfl_xor(y, 2);
            if (ks == 0) bufA[n * 128 + c] = y + bias;
        }
    }
    __syncthreads();

    // ---- phase 2b: instance-norm + style on bufA (gamma=consts[0..], beta=consts[128..]), leaky ----
    {
        const float g1 = consts[lane], b1 = consts[128 + lane];
        const float g2 = consts[lane + 64], b2 = consts[128 + lane + 64];
        for (int n = wv; n < TN; n += 8) {
            float v1 = bufA[n * 128 + lane], v2 = bufA[n * 128 + lane + 64];
            float s = v1 + v2, s2 = v1 * v1 + v2 * v2;
            #pragma unroll
            for (int d = 1; d < 64; d <<= 1) { s += __shfl_xor(s, d); s2 += __shfl_xor(s2, d); }
            float mu = s * 0.0078125f;
            float var = s2 * 0.0078125f - mu * mu;
            float rs = rsqrtf(var + 1e-5f);
            float o1 = g1 * ((v1 - mu) * rs) + b1;
            float o2 = g2 * ((v2 - mu) * rs) + b2;
            bufA[n * 128 + lane]      = o1 > 0.f ? o1 : 0.01f * o1;
            bufA[n * 128 + lane + 64] = o2 > 0.f ? o2 : 0.01f * o2;
        }
    }
    __syncthreads();

    // ---- phase 3: bufB = relu(bufB + bufA + cat2(bufA) + c2b) ----
    {
        float4 Wr[8];
        const float4* W4 = (const float4*)c2W + c * 32;
        #pragma unroll
        for (int j = 0; j < 8; j++) Wr[j] = W4[j * 4 + ks];
        const float bias = c2b[c];
        for (int n = 0; n < TN; n++) {
            const float4* h4 = (const float4*)(bufA + n * 128);
            float y = 0.f;
            #pragma unroll
            for (int j = 0; j < 8; j++) {
                float4 h = h4[j * 4 + ks];
                y += Wr[j].x * h.x + Wr[j].y * h.y + Wr[j].z * h.z + Wr[j].w * h.w;
            }
            y += __shfl_xor(y, 1); y += __shfl_xor(y, 2);
            if (ks == 0) {
                float u = bufB[n * 128 + c] + bufA[n * 128 + c] + y + bias;
                bufB[n * 128 + c] = u > 0.f ? u : 0.f;
            }
        }
    }
    __syncthreads();

    // ---- phase 4: bufA = fin0(bufB) + eb_f0 ----
    {
        float4 Wr[8];
        const float4* W4 = (const float4*)f0W + c * 32;
        #pragma unroll
        for (int j = 0; j < 8; j++) Wr[j] = W4[j * 4 + ks];
        const float bias = consts[768 + c];
        for (int n = 0; n < TN; n++) {
            const float4* h4 = (const float4*)(bufB + n * 128);
            float y = 0.f;
            #pragma unroll
            for (int j = 0; j < 8; j++) {
                float4 h = h4[j * 4 + ks];
                y += Wr[j].x * h.x + Wr[j].y * h.y + Wr[j].z * h.z + Wr[j].w * h.w;
            }
            y += __shfl_xor(y, 1); y += __shfl_xor(y, 2);
            if (ks == 0) bufA[n * 128 + c] = y + bias;
        }
    }
    __syncthreads();

    // ---- phase 4b: instance-norm + style on bufA (g=consts[256..], b=consts[384..]), leaky ----
    {
        const float g1 = consts[256 + lane], b1 = consts[384 + lane];
        const float g2 = consts[256 + lane + 64], b2 = consts[384 + lane + 64];
        for (int n = wv; n < TN; n += 8) {
            float v1 = bufA[n * 128 + lane], v2 = bufA[n * 128 + lane + 64];
            float s = v1 + v2, s2 = v1 * v1 + v2 * v2;
            #pragma unroll
            for (int d = 1; d < 64; d <<= 1) { s += __shfl_xor(s, d); s2 += __shfl_xor(s2, d); }
            float mu = s * 0.0078125f;
            float var = s2 * 0.0078125f - mu * mu;
            float rs = rsqrtf(var + 1e-5f);
            float o1 = g1 * ((v1 - mu) * rs) + b1;
            float o2 = g2 * ((v2 - mu) * rs) + b2;
            bufA[n * 128 + lane]      = o1 > 0.f ? o1 : 0.01f * o1;
            bufA[n * 128 + lane + 64] = o2 > 0.f ? o2 : 0.01f * o2;
        }
    }
    __syncthreads();

    // ---- phase 5: bufB[n*128 + c] (c<64) = fin1(bufA) + eb_f1 ----
    if (t < 256) {
        float4 Wr[8];
        const float4* W4 = (const float4*)f1W + c * 32;   // c in 0..63 here
        #pragma unroll
        for (int j = 0; j < 8; j++) Wr[j] = W4[j * 4 + ks];
        const float bias = consts[896 + c];
        for (int n = 0; n < TN; n++) {
            const float4* h4 = (const float4*)(bufA + n * 128);
            float y = 0.f;
            #pragma unroll
            for (int j = 0; j < 8; j++) {
                float4 h = h4[j * 4 + ks];
                y += Wr[j].x * h.x + Wr[j].y * h.y + Wr[j].z * h.z + Wr[j].w * h.w;
            }
            y += __shfl_xor(y, 1); y += __shfl_xor(y, 2);
            if (ks == 0) bufB[n * 128 + c] = y + bias;
        }
    }
    __syncthreads();

    // ---- phase 5b: instance-norm over 64 + style + leaky, write out ----
    {
        const float g = consts[512 + lane], be = consts[576 + lane];
        for (int n = wv; n < TN; n += 8) {
            float v = bufB[n * 128 + lane];   // lane 0..63 == channel
            float s = v, s2 = v * v;
            #pragma unroll
            for (int d = 1; d < 64; d <<= 1) { s += __shfl_xor(s, d); s2 += __shfl_xor(s2, d); }
            float mu = s * 0.015625f;
            float var = s2 * 0.015625f - mu * mu;
            float rs = rsqrtf(var + 1e-5f);
            float o = g * ((v - mu) * rs) + be;
            o = o > 0.f ? o : 0.01f * o;
            out[(size_t)(nbase + n) * 64 + lane] = o;
        }
    }
}

extern "C" void kernel_launch(void* const* d_in, const int* in_sizes, int n_in,
                              void* d_out, int out_size, void* d_ws, size_t ws_size,
                              hipStream_t stream)
{
    const float* x       = (const float*)d_in[0];
    const float* w       = (const float*)d_in[1];
    const int*   ei      = (const int*)  d_in[2];
    const float* Wa      = (const float*)d_in[3];
    const float* ba      = (const float*)d_in[4];
    const float* n0W     = (const float*)d_in[5];
    const float* n0b     = (const float*)d_in[6];
    const float* n0aW    = (const float*)d_in[7];
    const float* n0ab    = (const float*)d_in[8];
    const float* n0ns    = (const float*)d_in[9];
    const float* n0noise = (const float*)d_in[10];
    const float* c1W     = (const float*)d_in[11];
    const float* c1b     = (const float*)d_in[12];
    const float* c2W     = (const float*)d_in[13];
    const float* c2b     = (const float*)d_in[14];
    const float* f0W     = (const float*)d_in[15];
    const float* f0b     = (const float*)d_in[16];
    const float* f0aW    = (const float*)d_in[17];
    const float* f0ab    = (const float*)d_in[18];
    const float* f0ns    = (const float*)d_in[19];
    const float* f0noise = (const float*)d_in[20];
    const float* f1W     = (const float*)d_in[21];
    const float* f1b     = (const float*)d_in[22];
    const float* f1aW    = (const float*)d_in[23];
    const float* f1ab    = (const float*)d_in[24];
    const float* f1ns    = (const float*)d_in[25];
    const float* f1noise = (const float*)d_in[26];

    float* agg    = (float*)d_ws;                 // NN*128 floats = 32 MB
    float* consts = agg + (size_t)NN * 128;       // 960 floats

    style_consts_k<<<1, 256, 0, stream>>>(w, n0aW, n0ab, f0aW, f0ab, f1aW, f1ab,
                                          n0b, n0noise, n0ns, f0b, f0noise, f0ns,
                                          f1b, f1noise, f1ns, consts);
    init_agg_k<<<NN * 32 / 256, 256, 0, stream>>>((float4*)agg, (const float4*)ba);
    scatter_k<<<EE * 32 / 256, 256, 0, stream>>>(ei, (const float4*)Wa, agg);
    fused_k<<<NN / TN, 512, 0, stream>>>(x, agg, c1W, c1b, n0W, c2W, c2b, f0W, f1W,
                                         consts, (float*)d_out);
}

// Round 2
// 466.615 us; speedup vs baseline: 4.3566x; 4.3566x over previous
//
#include <hip/hip_runtime.h>

#define NN 65536
#define EE 1048576
#define TN 32   // nodes per block in fused kernel

// ---------------- style constants (tiny, one block) ----------------
// consts layout (floats):
//   0: g_n0[128]   128: b_n0[128]
// 256: g_f0[128]   384: b_f0[128]
// 512: g_f1[64]    576: b_f1[64]
// 640: eb_n0[128]  768: eb_f0[128]  896: eb_f1[64]
__global__ void style_consts_k(const float* __restrict__ w,
    const float* __restrict__ n0_aW, const float* __restrict__ n0_ab,
    const float* __restrict__ f0_aW, const float* __restrict__ f0_ab,
    const float* __restrict__ f1_aW, const float* __restrict__ f1_ab,
    const float* __restrict__ n0_b, const float* __restrict__ n0_noise, const float* __restrict__ n0_ns,
    const float* __restrict__ f0_b, const float* __restrict__ f0_noise, const float* __restrict__ f0_ns,
    const float* __restrict__ f1_b, const float* __restrict__ f1_noise, const float* __restrict__ f1_ns,
    float* __restrict__ consts)
{
    int t = threadIdx.x;
    for (int j = t; j < 640; j += 256) {
        const float* aW; const float* ab; int row; int off;
        if (j < 256)      { aW = n0_aW; ab = n0_ab; row = j;       off = 0;   }
        else if (j < 512) { aW = f0_aW; ab = f0_ab; row = j - 256; off = 256; }
        else              { aW = f1_aW; ab = f1_ab; row = j - 512; off = 512; }
        float s = 0.f;
        for (int k = 0; k < 128; k++) s += w[k] * aW[row * 128 + k];
        consts[off + row] = s + ab[row];
    }
    if (t < 128) consts[640 + t] = n0_b[t] + n0_noise[t] * n0_ns[0];
    if (t < 128) consts[768 + t] = f0_b[t] + f0_noise[t] * f0_ns[0];
    if (t < 64)  consts[896 + t] = f1_b[t] + f1_noise[t] * f1_ns[0];
}

// ---------------- degree histogram ----------------
__global__ void hist_k(const int* __restrict__ ei, int* __restrict__ deg)
{
    int e = blockIdx.x * 256 + threadIdx.x;
    atomicAdd(&deg[ei[EE + e]], 1);
}

// ---------------- exclusive scan of 65536 degrees (one block) ----------------
__global__ __launch_bounds__(1024) void scan_k(const int* __restrict__ deg,
                                               int* __restrict__ offs,
                                               int* __restrict__ cursor)
{
    __shared__ int part[1024];
    const int t = threadIdx.x;
    const int base = t * 64;
    int s = 0;
    #pragma unroll 8
    for (int i = 0; i < 64; i++) s += deg[base + i];
    part[t] = s;
    __syncthreads();
    // inclusive scan of part[]
    for (int d = 1; d < 1024; d <<= 1) {
        int v = (t >= d) ? part[t - d] : 0;
        __syncthreads();
        part[t] += v;
        __syncthreads();
    }
    int pre = (t == 0) ? 0 : part[t - 1];
    for (int i = 0; i < 64; i++) {
        offs[base + i] = pre;
        cursor[base + i] = pre;
        pre += deg[base + i];
    }
}

// ---------------- CSR fill: csr[slot] = src ----------------
__global__ void fill_k(const int* __restrict__ ei, int* __restrict__ cursor,
                       int* __restrict__ csr)
{
    int e = blockIdx.x * 256 + threadIdx.x;
    int src = ei[e];
    int dst = ei[EE + e];
    int slot = atomicAdd(&cursor[dst], 1);
    csr[slot] = src;
}

// ---------------- gather: agg[n] = ba + sum_{e in CSR(n)} Wa[src_e] ----------------
__global__ void gather_k(const int* __restrict__ csr, const int* __restrict__ offs,
                         const int* __restrict__ deg,
                         const float4* __restrict__ Wa4, const float4* __restrict__ ba4,
                         float4* __restrict__ agg4)
{
    int tid = blockIdx.x * 256 + threadIdx.x;   // NN*32 threads
    int node = tid >> 5, q = tid & 31;
    int beg = offs[node], d = deg[node];
    float4 acc = ba4[q];
    float4 acc2 = make_float4(0.f, 0.f, 0.f, 0.f);
    int j = 0;
    for (; j + 1 < d; j += 2) {
        int s0 = csr[beg + j], s1 = csr[beg + j + 1];
        float4 v0 = Wa4[(size_t)s0 * 32 + q];
        float4 v1 = Wa4[(size_t)s1 * 32 + q];
        acc.x += v0.x; acc.y += v0.y; acc.z += v0.z; acc.w += v0.w;
        acc2.x += v1.x; acc2.y += v1.y; acc2.z += v1.z; acc2.w += v1.w;
    }
    if (j < d) {
        int s0 = csr[beg + j];
        float4 v0 = Wa4[(size_t)s0 * 32 + q];
        acc.x += v0.x; acc.y += v0.y; acc.z += v0.z; acc.w += v0.w;
    }
    acc.x += acc2.x; acc.y += acc2.y; acc.z += acc2.z; acc.w += acc2.w;
    agg4[(size_t)node * 32 + q] = acc;
}

// ---------------- fused per-node pipeline ----------------
// 512 threads: c = t>>2 (0..127 output channel), ks = t&3 (k-slice).
__global__ __launch_bounds__(512) void fused_k(
    const float* __restrict__ x, const float* __restrict__ agg,
    const float* __restrict__ c1W, const float* __restrict__ c1b,
    const float* __restrict__ n0W,
    const float* __restrict__ c2W, const float* __restrict__ c2b,
    const float* __restrict__ f0W, const float* __restrict__ f1W,
    const float* __restrict__ consts, float* __restrict__ out)
{
    __shared__ float bufA[TN * 128];
    __shared__ float bufB[TN * 128];
    __shared__ float bufX[TN * 64];

    const int t = threadIdx.x;
    const int nbase = blockIdx.x * TN;
    const int c = t >> 2, ks = t & 3;
    const int wv = t >> 6, lane = t & 63;

    // stage agg rows and x rows into LDS (coalesced float4)
    {
        const float4* agg4 = (const float4*)agg + (size_t)nbase * 32;
        float4* bA4 = (float4*)bufA;
        for (int i = t; i < TN * 32; i += 512) bA4[i] = agg4[i];
        const float4* xx4 = (const float4*)x + (size_t)nbase * 16;
        float4* bX4 = (float4*)bufX;
        for (int i = t; i < TN * 16; i += 512) bX4[i] = xx4[i];
    }
    __syncthreads();

    // ---- phase 1: bufB = bufA + cat1(bufA) + c1b ----
    {
        float4 Wr[8];
        const float4* W4 = (const float4*)c1W + c * 32;
        #pragma unroll
        for (int j = 0; j < 8; j++) Wr[j] = W4[j * 4 + ks];
        const float bias = c1b[c];
        for (int n = 0; n < TN; n++) {
            const float4* h4 = (const float4*)(bufA + n * 128);
            float y = 0.f;
            #pragma unroll
            for (int j = 0; j < 8; j++) {
                float4 h = h4[j * 4 + ks];
                y += Wr[j].x * h.x + Wr[j].y * h.y + Wr[j].z * h.z + Wr[j].w * h.w;
            }
            y += __shfl_xor(y, 1); y += __shfl_xor(y, 2);
            if (ks == 0) bufB[n * 128 + c] = bufA[n * 128 + c] + y + bias;
        }
    }
    __syncthreads();

    // ---- phase 2: bufA = node0(bufX) + eb_n0 ----
    {
        float4 Wr[4];
        const float4* W4 = (const float4*)n0W + c * 16;
        #pragma unroll
        for (int j = 0; j < 4; j++) Wr[j] = W4[j * 4 + ks];
        const float bias = consts[640 + c];
        for (int n = 0; n < TN; n++) {
            const float4* h4 = (const float4*)(bufX + n * 64);
            float y = 0.f;
            #pragma unroll
            for (int j = 0; j < 4; j++) {
                float4 h = h4[j * 4 + ks];
                y += Wr[j].x * h.x + Wr[j].y * h.y + Wr[j].z * h.z + Wr[j].w * h.w;
            }
            y += __shfl_xor(y, 1); y += __shfl_xor(y, 2);
            if (ks == 0) bufA[n * 128 + c] = y + bias;
        }
    }
    __syncthreads();

    // ---- phase 2b: instance-norm + style + leaky ----
    {
        const float g1 = consts[lane], b1 = consts[128 + lane];
        const float g2 = consts[lane + 64], b2 = consts[128 + lane + 64];
        for (int n = wv; n < TN; n += 8) {
            float v1 = bufA[n * 128 + lane], v2 = bufA[n * 128 + lane + 64];
            float s = v1 + v2, s2 = v1 * v1 + v2 * v2;
            #pragma unroll
            for (int d = 1; d < 64; d <<= 1) { s += __shfl_xor(s, d); s2 += __shfl_xor(s2, d); }
            float mu = s * 0.0078125f;
            float var = s2 * 0.0078125f - mu * mu;
            float rs = rsqrtf(var + 1e-5f);
            float o1 = g1 * ((v1 - mu) * rs) + b1;
            float o2 = g2 * ((v2 - mu) * rs) + b2;
            bufA[n * 128 + lane]      = o1 > 0.f ? o1 : 0.01f * o1;
            bufA[n * 128 + lane + 64] = o2 > 0.f ? o2 : 0.01f * o2;
        }
    }
    __syncthreads();

    // ---- phase 3: bufB = relu(bufB + bufA + cat2(bufA) + c2b) ----
    {
        float4 Wr[8];
        const float4* W4 = (const float4*)c2W + c * 32;
        #pragma unroll
        for (int j = 0; j < 8; j++) Wr[j] = W4[j * 4 + ks];
        const float bias = c2b[c];
        for (int n = 0; n < TN; n++) {
            const float4* h4 = (const float4*)(bufA + n * 128);
            float y = 0.f;
            #pragma unroll
            for (int j = 0; j < 8; j++) {
                float4 h = h4[j * 4 + ks];
                y += Wr[j].x * h.x + Wr[j].y * h.y + Wr[j].z * h.z + Wr[j].w * h.w;
            }
            y += __shfl_xor(y, 1); y += __shfl_xor(y, 2);
            if (ks == 0) {
                float u = bufB[n * 128 + c] + bufA[n * 128 + c] + y + bias;
                bufB[n * 128 + c] = u > 0.f ? u : 0.f;
            }
        }
    }
    __syncthreads();

    // ---- phase 4: bufA = fin0(bufB) + eb_f0 ----
    {
        float4 Wr[8];
        const float4* W4 = (const float4*)f0W + c * 32;
        #pragma unroll
        for (int j = 0; j < 8; j++) Wr[j] = W4[j * 4 + ks];
        const float bias = consts[768 + c];
        for (int n = 0; n < TN; n++) {
            const float4* h4 = (const float4*)(bufB + n * 128);
            float y = 0.f;
            #pragma unroll
            for (int j = 0; j < 8; j++) {
                float4 h = h4[j * 4 + ks];
                y += Wr[j].x * h.x + Wr[j].y * h.y + Wr[j].z * h.z + Wr[j].w * h.w;
            }
            y += __shfl_xor(y, 1); y += __shfl_xor(y, 2);
            if (ks == 0) bufA[n * 128 + c] = y + bias;
        }
    }
    __syncthreads();

    // ---- phase 4b: instance-norm + style + leaky ----
    {
        const float g1 = consts[256 + lane], b1 = consts[384 + lane];
        const float g2 = consts[256 + lane + 64], b2 = consts[384 + lane + 64];
        for (int n = wv; n < TN; n += 8) {
            float v1 = bufA[n * 128 + lane], v2 = bufA[n * 128 + lane + 64];
            float s = v1 + v2, s2 = v1 * v1 + v2 * v2;
            #pragma unroll
            for (int d = 1; d < 64; d <<= 1) { s += __shfl_xor(s, d); s2 += __shfl_xor(s2, d); }
            float mu = s * 0.0078125f;
            float var = s2 * 0.0078125f - mu * mu;
            float rs = rsqrtf(var + 1e-5f);
            float o1 = g1 * ((v1 - mu) * rs) + b1;
            float o2 = g2 * ((v2 - mu) * rs) + b2;
            bufA[n * 128 + lane]      = o1 > 0.f ? o1 : 0.01f * o1;
            bufA[n * 128 + lane + 64] = o2 > 0.f ? o2 : 0.01f * o2;
        }
    }
    __syncthreads();

    // ---- phase 5: bufB[n*128 + c] (c<64) = fin1(bufA) + eb_f1 ----
    if (t < 256) {
        float4 Wr[8];
        const float4* W4 = (const float4*)f1W + c * 32;   // c in 0..63 here
        #pragma unroll
        for (int j = 0; j < 8; j++) Wr[j] = W4[j * 4 + ks];
        const float bias = consts[896 + c];
        for (int n = 0; n < TN; n++) {
            const float4* h4 = (const float4*)(bufA + n * 128);
            float y = 0.f;
            #pragma unroll
            for (int j = 0; j < 8; j++) {
                float4 h = h4[j * 4 + ks];
                y += Wr[j].x * h.x + Wr[j].y * h.y + Wr[j].z * h.z + Wr[j].w * h.w;
            }
            y += __shfl_xor(y, 1); y += __shfl_xor(y, 2);
            if (ks == 0) bufB[n * 128 + c] = y + bias;
        }
    }
    __syncthreads();

    // ---- phase 5b: instance-norm over 64 + style + leaky, write out ----
    {
        const float g = consts[512 + lane], be = consts[576 + lane];
        for (int n = wv; n < TN; n += 8) {
            float v = bufB[n * 128 + lane];   // lane 0..63 == channel
            float s = v, s2 = v * v;
            #pragma unroll
            for (int d = 1; d < 64; d <<= 1) { s += __shfl_xor(s, d); s2 += __shfl_xor(s2, d); }
            float mu = s * 0.015625f;
            float var = s2 * 0.015625f - mu * mu;
            float rs = rsqrtf(var + 1e-5f);
            float o = g * ((v - mu) * rs) + be;
            o = o > 0.f ? o : 0.01f * o;
            out[(size_t)(nbase + n) * 64 + lane] = o;
        }
    }
}

extern "C" void kernel_launch(void* const* d_in, const int* in_sizes, int n_in,
                              void* d_out, int out_size, void* d_ws, size_t ws_size,
                              hipStream_t stream)
{
    const float* x       = (const float*)d_in[0];
    const float* w       = (const float*)d_in[1];
    const int*   ei      = (const int*)  d_in[2];
    const float* Wa      = (const float*)d_in[3];
    const float* ba      = (const float*)d_in[4];
    const float* n0W     = (const float*)d_in[5];
    const float* n0b     = (const float*)d_in[6];
    const float* n0aW    = (const float*)d_in[7];
    const float* n0ab    = (const float*)d_in[8];
    const float* n0ns    = (const float*)d_in[9];
    const float* n0noise = (const float*)d_in[10];
    const float* c1W     = (const float*)d_in[11];
    const float* c1b     = (const float*)d_in[12];
    const float* c2W     = (const float*)d_in[13];
    const float* c2b     = (const float*)d_in[14];
    const float* f0W     = (const float*)d_in[15];
    const float* f0b     = (const float*)d_in[16];
    const float* f0aW    = (const float*)d_in[17];
    const float* f0ab    = (const float*)d_in[18];
    const float* f0ns    = (const float*)d_in[19];
    const float* f0noise = (const float*)d_in[20];
    const float* f1W     = (const float*)d_in[21];
    const float* f1b     = (const float*)d_in[22];
    const float* f1aW    = (const float*)d_in[23];
    const float* f1ab    = (const float*)d_in[24];
    const float* f1ns    = (const float*)d_in[25];
    const float* f1noise = (const float*)d_in[26];

    // ws layout
    float* agg    = (float*)d_ws;                          // NN*128 floats = 32 MB
    int*   csr    = (int*)(agg + (size_t)NN * 128);        // EE ints = 4 MB
    int*   deg    = csr + EE;                              // NN ints
    int*   offs   = deg + NN;                              // NN ints
    int*   cursor = offs + NN;                             // NN ints
    float* consts = (float*)(cursor + NN);                 // 960 floats

    style_consts_k<<<1, 256, 0, stream>>>(w, n0aW, n0ab, f0aW, f0ab, f1aW, f1ab,
                                          n0b, n0noise, n0ns, f0b, f0noise, f0ns,
                                          f1b, f1noise, f1ns, consts);
    hipMemsetAsync(deg, 0, (size_t)NN * sizeof(int), stream);
    hist_k<<<EE / 256, 256, 0, stream>>>(ei, deg);
    scan_k<<<1, 1024, 0, stream>>>(deg, offs, cursor);
    fill_k<<<EE / 256, 256, 0, stream>>>(ei, cursor, csr);
    gather_k<<<NN * 32 / 256, 256, 0, stream>>>(csr, offs, deg, (const float4*)Wa,
                                                (const float4*)ba, (float4*)agg);
    fused_k<<<NN / TN, 512, 0, stream>>>(x, agg, c1W, c1b, n0W, c2W, c2b, f0W, f1W,
                                         consts, (float*)d_out);
}

// Round 5
// 333.621 us; speedup vs baseline: 6.0933x; 1.3986x over previous
//
#include <hip/hip_runtime.h>

#define NN 65536
#define EE 1048576
#define TN 32   // nodes per block in fused kernel

typedef short bf16x8 __attribute__((ext_vector_type(8)));
typedef float f32x4 __attribute__((ext_vector_type(4)));

__device__ __forceinline__ unsigned short rne_bf16(float f) {
    unsigned int u = __float_as_uint(f);
    unsigned int r = (u + 0x7FFFu + ((u >> 16) & 1u)) >> 16;
    return (unsigned short)r;
}
__device__ __forceinline__ float bf16f(unsigned short h) {
    return __uint_as_float(((unsigned int)h) << 16);
}
// XOR-swizzled LDS float index (bits 2-4 of float idx <- row) to break
// stride-128/stride-64 bank conflicts on MFMA A-fragment ds_read_b128.
__device__ __forceinline__ int swz(int n, int c, int stride) {
    return (n * stride + c) ^ ((n & 7) << 2);
}

// ---------------- style constants (tiny, one block) ----------------
// consts: 0:g_n0[128] 128:b_n0[128] 256:g_f0[128] 384:b_f0[128]
//         512:g_f1[64] 576:b_f1[64] 640:eb_n0[128] 768:eb_f0[128] 896:eb_f1[64]
__global__ void style_consts_k(const float* __restrict__ w,
    const float* __restrict__ n0_aW, const float* __restrict__ n0_ab,
    const float* __restrict__ f0_aW, const float* __restrict__ f0_ab,
    const float* __restrict__ f1_aW, const float* __restrict__ f1_ab,
    const float* __restrict__ n0_b, const float* __restrict__ n0_noise, const float* __restrict__ n0_ns,
    const float* __restrict__ f0_b, const float* __restrict__ f0_noise, const float* __restrict__ f0_ns,
    const float* __restrict__ f1_b, const float* __restrict__ f1_noise, const float* __restrict__ f1_ns,
    float* __restrict__ consts)
{
    int t = threadIdx.x;
    for (int j = t; j < 640; j += 256) {
        const float* aW; const float* ab; int row; int off;
        if (j < 256)      { aW = n0_aW; ab = n0_ab; row = j;       off = 0;   }
        else if (j < 512) { aW = f0_aW; ab = f0_ab; row = j - 256; off = 256; }
        else              { aW = f1_aW; ab = f1_ab; row = j - 512; off = 512; }
        float s = 0.f;
        for (int k = 0; k < 128; k++) s += w[k] * aW[row * 128 + k];
        consts[off + row] = s + ab[row];
    }
    if (t < 128) consts[640 + t] = n0_b[t] + n0_noise[t] * n0_ns[0];
    if (t < 128) consts[768 + t] = f0_b[t] + f0_noise[t] * f0_ns[0];
    if (t < 64)  consts[896 + t] = f1_b[t] + f1_noise[t] * f1_ns[0];
}

// ---------------- Wa f32 -> fixed-point int32 (scale 2^24) ----------------
// Integer sums exact => gather independent of CSR slot order (deterministic).
// Quant err 3e-8/elem == f32 noise floor. |Wa|max~0.11 -> 1.85M; deg<=~45 -> no overflow.
__global__ void quant_wa_k(const f32x4* __restrict__ Wa4, int4* __restrict__ WaQ4)
{
    int i = blockIdx.x * 256 + threadIdx.x;   // NN*32
    f32x4 v = Wa4[i];
    int4 o;
    o.x = __float2int_rn(v[0] * 16777216.f);
    o.y = __float2int_rn(v[1] * 16777216.f);
    o.z = __float2int_rn(v[2] * 16777216.f);
    o.w = __float2int_rn(v[3] * 16777216.f);
    WaQ4[i] = o;
}

// ---------------- weight fragments (bf16 triple split, MFMA B-layout) ----------------
// frag elem for (nt,kt,lane,j): B[k][c] = W[c][k], c = nt*16+(lane&15),
// k = kt*32 + (lane>>4)*8 + j.  Linear: ((kt*NT+nt)*64+lane)*8+j.
// v ~= F1 + F2 + F3 (bf16 each, err <= 2^-24|v|; bf16 exp range == f32: no denorm hazard)
// Ranges: c1[0,16384) +I | n0[16384,24576) | c2[24576,40960) +I | f0[40960,57344) | f1[57344,65536)
__global__ void prep_frags_k(const float* __restrict__ c1W, const float* __restrict__ n0W,
                             const float* __restrict__ c2W, const float* __restrict__ f0W,
                             const float* __restrict__ f1W,
                             unsigned short* __restrict__ F1, unsigned short* __restrict__ F2,
                             unsigned short* __restrict__ F3)
{
    int e = blockIdx.x * 256 + threadIdx.x;   // 65536
    const float* W; int NT, Kdim, base; bool addI = false; int e2;
    if (e < 16384)      { W = c1W; NT = 8; Kdim = 128; base = 0;     addI = true;  e2 = e; }
    else if (e < 24576) { W = n0W; NT = 8; Kdim = 64;  base = 16384; e2 = e - 16384; }
    else if (e < 40960) { W = c2W; NT = 8; Kdim = 128; base = 24576; addI = true;  e2 = e - 24576; }
    else if (e < 57344) { W = f0W; NT = 8; Kdim = 128; base = 40960; e2 = e - 40960; }
    else                { W = f1W; NT = 4; Kdim = 128; base = 57344; e2 = e - 57344; }
    int j = e2 & 7, l = (e2 >> 3) & 63, rest = e2 >> 9;
    int nt = rest % NT, kt = rest / NT;
    int c = nt * 16 + (l & 15);
    int k = kt * 32 + ((l >> 4) << 3) + j;
    float v = W[c * Kdim + k] + ((addI && c == k) ? 1.f : 0.f);
    unsigned short s1 = rne_bf16(v);
    float r1 = v - bf16f(s1);
    unsigned short s2 = rne_bf16(r1);
    float r2 = r1 - bf16f(s2);
    unsigned short s3 = rne_bf16(r2);
    F1[base + e2] = s1;
    F2[base + e2] = s2;
    F3[base + e2] = s3;
}

// ---------------- degree histogram ----------------
__global__ void hist_k(const int* __restrict__ ei, int* __restrict__ deg)
{
    int e = blockIdx.x * 256 + threadIdx.x;
    atomicAdd(&deg[ei[EE + e]], 1);
}

// ---------------- exclusive scan of 65536 degrees (one block) ----------------
__global__ __launch_bounds__(1024) void scan_k(const int* __restrict__ deg,
                                               int* __restrict__ offs,
                                               int* __restrict__ cursor)
{
    __shared__ int part[1024];
    const int t = threadIdx.x;
    const int base = t * 64;
    int s = 0;
    #pragma unroll 8
    for (int i = 0; i < 64; i++) s += deg[base + i];
    part[t] = s;
    __syncthreads();
    for (int d = 1; d < 1024; d <<= 1) {
        int v = (t >= d) ? part[t - d] : 0;
        __syncthreads();
        part[t] += v;
        __syncthreads();
    }
    int pre = (t == 0) ? 0 : part[t - 1];
    for (int i = 0; i < 64; i++) {
        offs[base + i] = pre;
        cursor[base + i] = pre;
        pre += deg[base + i];
    }
}

// ---------------- CSR fill (slot order nondeterministic; int sums => invariant) ----------------
__global__ void fill_k(const int* __restrict__ ei, int* __restrict__ cursor,
                       int* __restrict__ csr)
{
    int e = blockIdx.x * 256 + threadIdx.x;
    int src = ei[e];
    int dst = ei[EE + e];
    int slot = atomicAdd(&cursor[dst], 1);
    csr[slot] = src;
}

// ---------------- GEMM phase: C[32 x NT*16] = A[32 x KT*32] * Bfrags ----------------
// bf16 triple split both sides: a = a1+a2+a3, b = b1+b2+b3 (err 2^-24 each).
// 8 MFMAs: a1b1 -> acc0; {a1b2,a2b1,a1b3,a2b2,a3b1,a2b3,a3b2} -> acc1 (<=2^-8 scale).
// Dropped a3b3 ~ 2^-32. Result ~= f32-parity.
template<int KT, int NT, int NTILES, int ASTRIDE>
__device__ __forceinline__ void gemm_phase(const float* __restrict__ bufIn,
    const bf16x8* __restrict__ F1, const bf16x8* __restrict__ F2,
    const bf16x8* __restrict__ F3,
    int frag8, int mt, int nt0, int lane, f32x4* acc)
{
    f32x4 a0[NTILES], a1acc[NTILES];
    #pragma unroll
    for (int tt = 0; tt < NTILES; tt++) {
        a0[tt] = f32x4{0.f, 0.f, 0.f, 0.f};
        a1acc[tt] = f32x4{0.f, 0.f, 0.f, 0.f};
    }
    const int arow = mt * 16 + (lane & 15);
    const int kb0 = (lane >> 4) << 3;
    #pragma unroll
    for (int kt = 0; kt < KT; kt++) {
        int kb = kt * 32 + kb0;
        f32x4 x0 = *(const f32x4*)(bufIn + swz(arow, kb, ASTRIDE));
        f32x4 x1 = *(const f32x4*)(bufIn + swz(arow, kb + 4, ASTRIDE));
        bf16x8 av1, av2, av3;
        #pragma unroll
        for (int j = 0; j < 8; j++) {
            float f = (j < 4) ? x0[j] : x1[j - 4];
            unsigned short s1 = rne_bf16(f);
            float r1 = f - bf16f(s1);
            unsigned short s2 = rne_bf16(r1);
            float r2 = r1 - bf16f(s2);
            unsigned short s3 = rne_bf16(r2);
            av1[j] = (short)s1; av2[j] = (short)s2; av3[j] = (short)s3;
        }
        #pragma unroll
        for (int tt = 0; tt < NTILES; tt++) {
            int fi = frag8 + (kt * NT + nt0 + tt) * 64 + lane;
            bf16x8 b1 = F1[fi];
            bf16x8 b2 = F2[fi];
            bf16x8 b3 = F3[fi];
            a0[tt]    = __builtin_amdgcn_mfma_f32_16x16x32_bf16(av1, b1, a0[tt], 0, 0, 0);
            a1acc[tt] = __builtin_amdgcn_mfma_f32_16x16x32_bf16(av1, b2, a1acc[tt], 0, 0, 0);
            a1acc[tt] = __builtin_amdgcn_mfma_f32_16x16x32_bf16(av2, b1, a1acc[tt], 0, 0, 0);
            a1acc[tt] = __builtin_amdgcn_mfma_f32_16x16x32_bf16(av1, b3, a1acc[tt], 0, 0, 0);
            a1acc[tt] = __builtin_amdgcn_mfma_f32_16x16x32_bf16(av2, b2, a1acc[tt], 0, 0, 0);
            a1acc[tt] = __builtin_amdgcn_mfma_f32_16x16x32_bf16(av3, b1, a1acc[tt], 0, 0, 0);
            a1acc[tt] = __builtin_amdgcn_mfma_f32_16x16x32_bf16(av2, b3, a1acc[tt], 0, 0, 0);
            a1acc[tt] = __builtin_amdgcn_mfma_f32_16x16x32_bf16(av3, b2, a1acc[tt], 0, 0, 0);
        }
    }
    #pragma unroll
    for (int tt = 0; tt < NTILES; tt++) {
        #pragma unroll
        for (int i = 0; i < 4; i++)
            acc[tt][i] = a0[tt][i] + a1acc[tt][i];
    }
}

// ---------------- fused per-node pipeline (gather + 5 GEMMs + 3 norms) ----------------
__global__ __launch_bounds__(512) void fused_k(
    const float* __restrict__ x, const int* __restrict__ WaQ,
    const float* __restrict__ ba,
    const int* __restrict__ csr, const int* __restrict__ offs, const int* __restrict__ deg,
    const unsigned short* __restrict__ F1_, const unsigned short* __restrict__ F2_,
    const unsigned short* __restrict__ F3_,
    const float* __restrict__ c1b, const float* __restrict__ c2b,
    const float* __restrict__ consts, float* __restrict__ out)
{
    __shared__ float bufA[TN * 128];
    __shared__ float bufB[TN * 128];
    __shared__ float bufX[TN * 64];

    const int t = threadIdx.x;
    const int nbase = blockIdx.x * TN;
    const int wv = t >> 6, lane = t & 63;
    const bf16x8* F1 = (const bf16x8*)F1_;
    const bf16x8* F2 = (const bf16x8*)F2_;
    const bf16x8* F3 = (const bf16x8*)F3_;

    // ---- stage x into bufX (swizzled) ----
    {
        int n = t >> 4, c4 = (t & 15) * 4;
        f32x4 v = *(const f32x4*)(x + (size_t)(nbase + n) * 64 + c4);
        *(f32x4*)(bufX + swz(n, c4, 64)) = v;
    }
    // ---- gather: bufA[n] = ba + 2^-24 * sum WaQ[src]  (exact int sums) ----
    {
        int ln = t >> 4, part = t & 15;
        int node = nbase + ln;
        int beg = offs[node], d = deg[node];
        int ai[8] = {0, 0, 0, 0, 0, 0, 0, 0};
        const int4* wq = (const int4*)WaQ;
        for (int jj = 0; jj < d; jj++) {
            int s = csr[beg + jj];
            int4 v0 = wq[(size_t)s * 32 + part * 2];
            int4 v1 = wq[(size_t)s * 32 + part * 2 + 1];
            ai[0] += v0.x; ai[1] += v0.y; ai[2] += v0.z; ai[3] += v0.w;
            ai[4] += v1.x; ai[5] += v1.y; ai[6] += v1.z; ai[7] += v1.w;
        }
        const f32x4* ba4 = (const f32x4*)ba;
        f32x4 b0 = ba4[part * 2], b1 = ba4[part * 2 + 1];
        const float sc = 5.9604644775390625e-8f;   // 2^-24
        f32x4 w0 = {b0[0] + (float)ai[0] * sc, b0[1] + (float)ai[1] * sc,
                    b0[2] + (float)ai[2] * sc, b0[3] + (float)ai[3] * sc};
        f32x4 w1 = {b1[0] + (float)ai[4] * sc, b1[1] + (float)ai[5] * sc,
                    b1[2] + (float)ai[6] * sc, b1[3] + (float)ai[7] * sc};
        *(f32x4*)(bufA + swz(ln, part * 8, 128)) = w0;
        *(f32x4*)(bufA + swz(ln, part * 8 + 4, 128)) = w1;
    }
    __syncthreads();

    const int mt = wv >> 2;
    const int nt0 = (wv & 3) * 2;
    const int cl = lane & 15;
    const int rb = mt * 16 + ((lane >> 4) << 2);

    // ---- P1: bufB = (I+c1W)·bufA + c1b ----
    {
        f32x4 acc[2];
        gemm_phase<4, 8, 2, 128>(bufA, F1, F2, F3, 0, mt, nt0, lane, acc);
        #pragma unroll
        for (int tt = 0; tt < 2; tt++) {
            int c = (nt0 + tt) * 16 + cl;
            float bias = c1b[c];
            #pragma unroll
            for (int i = 0; i < 4; i++)
                bufB[swz(rb + i, c, 128)] = acc[tt][i] + bias;
        }
    }
    __syncthreads();

    // ---- P2: bufA = n0W·bufX + eb_n0 ----
    {
        f32x4 acc[2];
        gemm_phase<2, 8, 2, 64>(bufX, F1, F2, F3, 2048, mt, nt0, lane, acc);
        #pragma unroll
        for (int tt = 0; tt < 2; tt++) {
            int c = (nt0 + tt) * 16 + cl;
            float eb = consts[640 + c];
            #pragma unroll
            for (int i = 0; i < 4; i++)
                bufA[swz(rb + i, c, 128)] = acc[tt][i] + eb;
        }
    }
    __syncthreads();

    // ---- norm on bufA (gamma consts[0..], beta consts[128..]) + leaky ----
    {
        const float g1 = consts[lane], b1 = consts[128 + lane];
        const float g2 = consts[lane + 64], b2 = consts[128 + lane + 64];
        for (int n = wv; n < TN; n += 8) {
            int iA = swz(n, lane, 128), iB = swz(n, lane + 64, 128);
            float v1 = bufA[iA], v2 = bufA[iB];
            float s = v1 + v2, s2 = v1 * v1 + v2 * v2;
            #pragma unroll
            for (int d = 1; d < 64; d <<= 1) { s += __shfl_xor(s, d); s2 += __shfl_xor(s2, d); }
            float mu = s * 0.0078125f;
            float var = s2 * 0.0078125f - mu * mu;
            float rs = rsqrtf(var + 1e-5f);
            float o1 = g1 * ((v1 - mu) * rs) + b1;
            float o2 = g2 * ((v2 - mu) * rs) + b2;
            bufA[iA] = o1 > 0.f ? o1 : 0.01f * o1;
            bufA[iB] = o2 > 0.f ? o2 : 0.01f * o2;
        }
    }
    __syncthreads();

    // ---- P3: bufB = relu(bufB + (I+c2W)·bufA + c2b) ----
    {
        f32x4 acc[2];
        gemm_phase<4, 8, 2, 128>(bufA, F1, F2, F3, 3072, mt, nt0, lane, acc);
        #pragma unroll
        for (int tt = 0; tt < 2; tt++) {
            int c = (nt0 + tt) * 16 + cl;
            float bias = c2b[c];
            #pragma unroll
            for (int i = 0; i < 4; i++) {
                int id = swz(rb + i, c, 128);
                float u = acc[tt][i] + bufB[id] + bias;
                bufB[id] = u > 0.f ? u : 0.f;
            }
        }
    }
    __syncthreads();

    // ---- P4: bufA = f0W·bufB + eb_f0 ----
    {
        f32x4 acc[2];
        gemm_phase<4, 8, 2, 128>(bufB, F1, F2, F3, 5120, mt, nt0, lane, acc);
        #pragma unroll
        for (int tt = 0; tt < 2; tt++) {
            int c = (nt0 + tt) * 16 + cl;
            float eb = consts[768 + c];
            #pragma unroll
            for (int i = 0; i < 4; i++)
                bufA[swz(rb + i, c, 128)] = acc[tt][i] + eb;
        }
    }
    __syncthreads();

    // ---- norm on bufA (gamma consts[256..], beta consts[384..]) + leaky ----
    {
        const float g1 = consts[256 + lane], b1 = consts[384 + lane];
        const float g2 = consts[256 + lane + 64], b2 = consts[384 + lane + 64];
        for (int n = wv; n < TN; n += 8) {
            int iA = swz(n, lane, 128), iB = swz(n, lane + 64, 128);
            float v1 = bufA[iA], v2 = bufA[iB];
            float s = v1 + v2, s2 = v1 * v1 + v2 * v2;
            #pragma unroll
            for (int d = 1; d < 64; d <<= 1) { s += __shfl_xor(s, d); s2 += __shfl_xor(s2, d); }
            float mu = s * 0.0078125f;
            float var = s2 * 0.0078125f - mu * mu;
            float rs = rsqrtf(var + 1e-5f);
            float o1 = g1 * ((v1 - mu) * rs) + b1;
            float o2 = g2 * ((v2 - mu) * rs) + b2;
            bufA[iA] = o1 > 0.f ? o1 : 0.01f * o1;
            bufA[iB] = o2 > 0.f ? o2 : 0.01f * o2;
        }
    }
    __syncthreads();

    // ---- P5: bufB[:, :64] = f1W·bufA + eb_f1 ----
    {
        f32x4 acc[1];
        int nt = wv & 3;   // 4 col tiles of 16 -> 64 outputs
        gemm_phase<4, 4, 1, 128>(bufA, F1, F2, F3, 7168, mt, nt, lane, acc);
        int c = nt * 16 + cl;
        float eb = consts[896 + c];
        #pragma unroll
        for (int i = 0; i < 4; i++)
            bufB[swz(rb + i, c, 128)] = acc[0][i] + eb;
    }
    __syncthreads();

    // ---- norm over 64 + style + leaky, write out ----
    {
        const float g = consts[512 + lane], be = consts[576 + lane];
        for (int n = wv; n < TN; n += 8) {
            float v = bufB[swz(n, lane, 128)];
            float s = v, s2 = v * v;
            #pragma unroll
            for (int d = 1; d < 64; d <<= 1) { s += __shfl_xor(s, d); s2 += __shfl_xor(s2, d); }
            float mu = s * 0.015625f;
            float var = s2 * 0.015625f - mu * mu;
            float rs = rsqrtf(var + 1e-5f);
            float o = g * ((v - mu) * rs) + be;
            o = o > 0.f ? o : 0.01f * o;
            out[(size_t)(nbase + n) * 64 + lane] = o;
        }
    }
}

extern "C" void kernel_launch(void* const* d_in, const int* in_sizes, int n_in,
                              void* d_out, int out_size, void* d_ws, size_t ws_size,
                              hipStream_t stream)
{
    const float* x       = (const float*)d_in[0];
    const float* w       = (const float*)d_in[1];
    const int*   ei      = (const int*)  d_in[2];
    const float* Wa      = (const float*)d_in[3];
    const float* ba      = (const float*)d_in[4];
    const float* n0W     = (const float*)d_in[5];
    const float* n0b     = (const float*)d_in[6];
    const float* n0aW    = (const float*)d_in[7];
    const float* n0ab    = (const float*)d_in[8];
    const float* n0ns    = (const float*)d_in[9];
    const float* n0noise = (const float*)d_in[10];
    const float* c1W     = (const float*)d_in[11];
    const float* c1b     = (const float*)d_in[12];
    const float* c2W     = (const float*)d_in[13];
    const float* c2b     = (const float*)d_in[14];
    const float* f0W     = (const float*)d_in[15];
    const float* f0b     = (const float*)d_in[16];
    const float* f0aW    = (const float*)d_in[17];
    const float* f0ab    = (const float*)d_in[18];
    const float* f0ns    = (const float*)d_in[19];
    const float* f0noise = (const float*)d_in[20];
    const float* f1W     = (const float*)d_in[21];
    const float* f1b     = (const float*)d_in[22];
    const float* f1aW    = (const float*)d_in[23];
    const float* f1ab    = (const float*)d_in[24];
    const float* f1ns    = (const float*)d_in[25];
    const float* f1noise = (const float*)d_in[26];

    // ws layout
    int*            WaQ = (int*)d_ws;                      // NN*128 ints = 32 MB
    unsigned short* F1  = (unsigned short*)(WaQ + (size_t)NN * 128);  // 65536 u16
    unsigned short* F2  = F1 + 65536;
    unsigned short* F3  = F2 + 65536;
    int*   csr    = (int*)(F3 + 65536);                    // EE ints = 4 MB
    int*   deg    = csr + EE;
    int*   offs   = deg + NN;
    int*   cursor = offs + NN;
    float* consts = (float*)(cursor + NN);                 // 960 floats

    style_consts_k<<<1, 256, 0, stream>>>(w, n0aW, n0ab, f0aW, f0ab, f1aW, f1ab,
                                          n0b, n0noise, n0ns, f0b, f0noise, f0ns,
                                          f1b, f1noise, f1ns, consts);
    quant_wa_k<<<NN * 32 / 256, 256, 0, stream>>>((const f32x4*)Wa, (int4*)WaQ);
    prep_frags_k<<<256, 256, 0, stream>>>(c1W, n0W, c2W, f0W, f1W, F1, F2, F3);
    hipMemsetAsync(deg, 0, (size_t)NN * sizeof(int), stream);
    hist_k<<<EE / 256, 256, 0, stream>>>(ei, deg);
    scan_k<<<1, 1024, 0, stream>>>(deg, offs, cursor);
    fill_k<<<EE / 256, 256, 0, stream>>>(ei, cursor, csr);
    fused_k<<<NN / TN, 512, 0, stream>>>(x, WaQ, ba, csr, offs, deg, F1, F2, F3,
                                         c1b, c2b, consts, (float*)d_out);
}